// Round 4
// baseline (4828.923 us; speedup 1.0000x reference)
//
#include <hip/hip_runtime.h>

#define T_TOK 2048
#define H_DIM 2048
#define F_DIM 7168
#define E_NUM 8
#define MAX_SLOTS 5120   // 4096 used slots + per-expert pad to 128

typedef __attribute__((ext_vector_type(8))) _Float16 f16x8;
typedef __attribute__((ext_vector_type(4))) float    f32x4;

// async global->LDS, 16B per lane; LDS dest wave-uniform base + lane*16
#define GLL(g, l) __builtin_amdgcn_global_load_lds(                          \
    (const __attribute__((address_space(1))) void*)(g),                      \
    (__attribute__((address_space(3))) void*)(l), 16, 0, 0)

// ---------------- small kernels ----------------

// fp32 -> fp16 bulk convert (hidden states only), 8 elems/thread
__global__ __launch_bounds__(256) void cvtx_kernel(const float* __restrict__ src,
                                                   _Float16* __restrict__ dst) {
    size_t i = ((size_t)blockIdx.x * 256 + threadIdx.x) * 8;
    float4 a = *(const float4*)(src + i);
    float4 b = *(const float4*)(src + i + 4);
    f16x8 h;
    h[0]=(_Float16)a.x; h[1]=(_Float16)a.y; h[2]=(_Float16)a.z; h[3]=(_Float16)a.w;
    h[4]=(_Float16)b.x; h[5]=(_Float16)b.y; h[6]=(_Float16)b.z; h[7]=(_Float16)b.w;
    *(f16x8*)(dst + i) = h;
}

__global__ __launch_bounds__(256) void router_kernel(
    const float* __restrict__ x, const float* __restrict__ wg,
    float* __restrict__ logits_out, int* __restrict__ tk_e,
    float* __restrict__ tk_w, int* __restrict__ meta) {
    int wave = threadIdx.x >> 6;
    int lane = threadIdx.x & 63;
    int t = blockIdx.x * 4 + wave;
    const float* xr = x + (size_t)t * H_DIM;

    float xv[32];
#pragma unroll
    for (int i = 0; i < 8; i++) {
        float4 v = *(const float4*)(xr + i * 256 + lane * 4);
        xv[i*4+0] = v.x; xv[i*4+1] = v.y; xv[i*4+2] = v.z; xv[i*4+3] = v.w;
    }
    float lg[E_NUM];
#pragma unroll
    for (int e = 0; e < E_NUM; e++) {
        const float* wr = wg + (size_t)e * H_DIM;
        float acc = 0.f;
#pragma unroll
        for (int i = 0; i < 8; i++) {
            float4 v = *(const float4*)(wr + i * 256 + lane * 4);
            acc += xv[i*4+0]*v.x + xv[i*4+1]*v.y + xv[i*4+2]*v.z + xv[i*4+3]*v.w;
        }
#pragma unroll
        for (int s = 32; s > 0; s >>= 1) acc += __shfl_xor(acc, s, 64);
        lg[e] = acc;
    }
    if (lane == 0) {
        float b0 = -3e38f, b1 = -3e38f; int i0 = 0, i1 = 0;
#pragma unroll
        for (int e = 0; e < E_NUM; e++) {
            float le = lg[e];
            if (le > b0)      { b1 = b0; i1 = i0; b0 = le; i0 = e; }
            else if (le > b1) { b1 = le; i1 = e; }
        }
        float w0 = 1.f / (1.f + __expf(b1 - b0));
        float w1v = 1.f - w0;
#pragma unroll
        for (int e = 0; e < E_NUM; e++) logits_out[(size_t)t * E_NUM + e] = lg[e];
        tk_e[t*2+0] = i0; tk_w[t*2+0] = w0;
        tk_e[t*2+1] = i1; tk_w[t*2+1] = w1v;
        atomicAdd(&meta[i0], 1);
        atomicAdd(&meta[i1], 1);
    }
}

// meta layout: [0..7]=cnt, [8..15]=cnt_pad128, [16..23]=base, [24..31]=fill
__global__ void scan_kernel(int* __restrict__ meta, int* __restrict__ slot_tok,
                            float* __restrict__ slot_w) {
    int lane = threadIdx.x;  // 64 threads
    int cnts[E_NUM], pads[E_NUM], bases[E_NUM];
    int run = 0;
#pragma unroll
    for (int e = 0; e < E_NUM; e++) {
        cnts[e] = meta[e];
        pads[e] = (cnts[e] + 127) & ~127;
        bases[e] = run;
        run += pads[e];
    }
    if (lane < E_NUM) { meta[8 + lane] = pads[lane]; meta[16 + lane] = bases[lane]; }
    for (int e = 0; e < E_NUM; e++)
        for (int i = cnts[e] + lane; i < pads[e]; i += 64) {
            slot_tok[bases[e] + i] = 0;
            slot_w[bases[e] + i] = 0.f;
        }
}

__global__ __launch_bounds__(256) void assign_kernel(
    const int* __restrict__ tk_e, const float* __restrict__ tk_w,
    int* __restrict__ meta, int* __restrict__ slot_tok, float* __restrict__ slot_w) {
    int t = blockIdx.x * 256 + threadIdx.x;
    if (t >= T_TOK) return;
#pragma unroll
    for (int k = 0; k < 2; k++) {
        int e = tk_e[t*2+k];
        int pos = atomicAdd(&meta[24 + e], 1);
        int s = meta[16 + e] + pos;
        slot_tok[s] = t;
        slot_w[s] = tk_w[t*2+k];
    }
}

// ---------------- ffn1: 128(M) x 64(F-cols, x2 for w1/w3) x K64 ----------------
// B tile rows 0..63 = w1[f], 64..127 = w3[f]; waves split M only (4x1);
// acc[m][n] pairs with acc[m][n+4] register-locally for silu.
__global__ __launch_bounds__(256, 4) void ffn1_kernel(
    const _Float16* __restrict__ xb, const float* __restrict__ w1,
    const float* __restrict__ w3, const int* __restrict__ slot_tok,
    const int* __restrict__ meta, _Float16* __restrict__ hbuf) {
    int e = blockIdx.z;
    int cntpad = meta[8 + e];
    int mb = blockIdx.y;
    if (mb * 128 >= cntpad) return;
    int base = meta[16 + e];
    int nb = blockIdx.x;

    __shared__ _Float16 sA[128][64];   // 16 KB (A fp16, GLL, source-swizzled)
    __shared__ _Float16 sB[128][64];   // 16 KB (B fp16, reg-staged, write-swizzled)
    char* sAc = (char*)&sA[0][0];
    char* sBc = (char*)&sB[0][0];

    int tid  = threadIdx.x;
    int lane = tid & 63;
    int wave = tid >> 6;              // 0..3, M-split
    int lr = lane & 15;
    int sg = lane >> 4;               // 0..3
    int sw7 = lane & 7;
    int bro0 = ((sg    ) ^ sw7) * 16; // swizzled 16B-slot byte offset, k-half 0
    int bro1 = ((sg + 4) ^ sw7) * 16; // k-half 1

    // ---- A staging (GLL, fp16): 4 chunks of 8 rows per wave, source pre-swizzled
    int rsub = lane >> 3;
    int sl = (lane & 7) ^ rsub;
    const _Float16* aG[4];
#pragma unroll
    for (int q = 0; q < 4; q++) {
        int row = mb * 128 + wave * 32 + q * 8 + rsub;
        int tok = slot_tok[base + row];
        aG[q] = xb + (size_t)tok * H_DIM + sl * 8;
    }

    // ---- B staging (reg, fp32->fp16): lane covers row=wave*32+(lane>>1), 32 floats
    int brow = wave * 32 + (lane >> 1);          // tile col 0..127
    const float* wsel = (brow < 64) ? w1 : w3;
    const float* bsrc = wsel + ((size_t)e * F_DIM + (size_t)nb * 64 + (brow & 63)) * H_DIM
                        + (lane & 1) * 32;
    int bwr[4];
#pragma unroll
    for (int q = 0; q < 4; q++)
        bwr[q] = brow * 128 + ((((lane & 1) * 4 + q) ^ (brow & 7)) * 16);

    f32x4 zero = {0.f, 0.f, 0.f, 0.f};
    f32x4 acc[2][8];
#pragma unroll
    for (int m = 0; m < 2; m++)
#pragma unroll
        for (int n = 0; n < 8; n++) acc[m][n] = zero;

    const int NT = H_DIM / 64;  // 32
    float4 br[8];
#pragma unroll
    for (int q = 0; q < 8; q++) br[q] = *(const float4*)(bsrc + q * 4);

    for (int t = 0; t < NT; ++t) {
        int k = t * 64;
        __builtin_amdgcn_sched_barrier(0);
        __builtin_amdgcn_s_barrier();          // prev tile fully consumed
        __builtin_amdgcn_sched_barrier(0);
        // convert staged B -> LDS (compiler waits the br loads)
#pragma unroll
        for (int q = 0; q < 4; q++) {
            float4 a = br[2*q], b = br[2*q+1];
            f16x8 p;
            p[0]=(_Float16)a.x; p[1]=(_Float16)a.y; p[2]=(_Float16)a.z; p[3]=(_Float16)a.w;
            p[4]=(_Float16)b.x; p[5]=(_Float16)b.y; p[6]=(_Float16)b.z; p[7]=(_Float16)b.w;
            *(f16x8*)(sBc + bwr[q]) = p;
        }
        // async A for this tile
#pragma unroll
        for (int q = 0; q < 4; q++) GLL(aG[q] + k, &sA[wave * 32 + q * 8][0]);
        // prefetch next B tile into regs (in flight across compute)
        if (t + 1 < NT) {
#pragma unroll
            for (int q = 0; q < 8; q++) br[q] = *(const float4*)(bsrc + k + 64 + q * 4);
            asm volatile("s_waitcnt vmcnt(8) lgkmcnt(0)" ::: "memory");
        } else {
            asm volatile("s_waitcnt vmcnt(0) lgkmcnt(0)" ::: "memory");
        }
        __builtin_amdgcn_sched_barrier(0);
        __builtin_amdgcn_s_barrier();
        __builtin_amdgcn_sched_barrier(0);
        // compute
        __builtin_amdgcn_s_setprio(1);
#pragma unroll
        for (int ks = 0; ks < 2; ks++) {
            int bro = ks ? bro1 : bro0;
            f16x8 bf[8];
#pragma unroll
            for (int n = 0; n < 8; n++)
                bf[n] = *(const f16x8*)(sBc + (n * 16 + lr) * 128 + bro);
#pragma unroll
            for (int m = 0; m < 2; m++) {
                f16x8 av = *(const f16x8*)(sAc + (wave * 32 + m * 16 + lr) * 128 + bro);
#pragma unroll
                for (int n = 0; n < 8; n++)
                    acc[m][n] = __builtin_amdgcn_mfma_f32_16x16x32_f16(av, bf[n], acc[m][n], 0, 0, 0);
            }
        }
        __builtin_amdgcn_s_setprio(0);
    }

    // epilogue: silu(a1)*a3 -> hbuf fp16
    int fb = nb * 64;
#pragma unroll
    for (int m = 0; m < 2; m++) {
#pragma unroll
        for (int j = 0; j < 4; j++) {
            int row = mb * 128 + wave * 32 + m * 16 + sg * 4 + j;
            size_t srow = (size_t)(base + row) * F_DIM;
#pragma unroll
            for (int n = 0; n < 4; n++) {
                float a1 = acc[m][n][j], a3 = acc[m][n + 4][j];
                float hv = a1 * a3 / (1.f + __expf(-a1));
                hbuf[srow + fb + n * 16 + lr] = (_Float16)hv;
            }
        }
    }
}

// ---------------- ffn2: 128(M) x 128(H-cols) x K64, w2 fp32 reg-staged ----------------
__global__ __launch_bounds__(256, 4) void ffn2_kernel(
    const _Float16* __restrict__ hbuf, const float* __restrict__ w2,
    const int* __restrict__ slot_tok, const float* __restrict__ slot_w,
    const int* __restrict__ meta, float* __restrict__ out) {
    int e = blockIdx.z;
    int cntpad = meta[8 + e];
    int mb = blockIdx.y;
    if (mb * 128 >= cntpad) return;
    int base = meta[16 + e];
    int nb = blockIdx.x;

    __shared__ _Float16 sA[128][64];
    __shared__ _Float16 sB[128][64];
    char* sAc = (char*)&sA[0][0];
    char* sBc = (char*)&sB[0][0];

    int tid  = threadIdx.x;
    int lane = tid & 63;
    int wave = tid >> 6;
    int wm = wave >> 1, wn = wave & 1;   // 2x2, 64x64 per wave
    int lr = lane & 15;
    int sg = lane >> 4;
    int sw7 = lane & 7;
    int bro0 = ((sg    ) ^ sw7) * 16;
    int bro1 = ((sg + 4) ^ sw7) * 16;

    int rsub = lane >> 3;
    int sl = (lane & 7) ^ rsub;
    int slot0 = base + mb * 128;
    const _Float16* aG[4];
#pragma unroll
    for (int q = 0; q < 4; q++)
        aG[q] = hbuf + (size_t)(slot0 + wave * 32 + q * 8 + rsub) * F_DIM + sl * 8;

    int brow = wave * 32 + (lane >> 1);
    const float* bsrc = w2 + ((size_t)e * H_DIM + (size_t)nb * 128 + brow) * F_DIM
                        + (lane & 1) * 32;
    int bwr[4];
#pragma unroll
    for (int q = 0; q < 4; q++)
        bwr[q] = brow * 128 + ((((lane & 1) * 4 + q) ^ (brow & 7)) * 16);

    f32x4 zero = {0.f, 0.f, 0.f, 0.f};
    f32x4 acc[4][4];
#pragma unroll
    for (int m = 0; m < 4; m++)
#pragma unroll
        for (int n = 0; n < 4; n++) acc[m][n] = zero;

    const int NT = F_DIM / 64;  // 112
    float4 br[8];
#pragma unroll
    for (int q = 0; q < 8; q++) br[q] = *(const float4*)(bsrc + q * 4);

    for (int t = 0; t < NT; ++t) {
        int k = t * 64;
        __builtin_amdgcn_sched_barrier(0);
        __builtin_amdgcn_s_barrier();
        __builtin_amdgcn_sched_barrier(0);
#pragma unroll
        for (int q = 0; q < 4; q++) {
            float4 a = br[2*q], b = br[2*q+1];
            f16x8 p;
            p[0]=(_Float16)a.x; p[1]=(_Float16)a.y; p[2]=(_Float16)a.z; p[3]=(_Float16)a.w;
            p[4]=(_Float16)b.x; p[5]=(_Float16)b.y; p[6]=(_Float16)b.z; p[7]=(_Float16)b.w;
            *(f16x8*)(sBc + bwr[q]) = p;
        }
#pragma unroll
        for (int q = 0; q < 4; q++) GLL(aG[q] + k, &sA[wave * 32 + q * 8][0]);
        if (t + 1 < NT) {
#pragma unroll
            for (int q = 0; q < 8; q++) br[q] = *(const float4*)(bsrc + k + 64 + q * 4);
            asm volatile("s_waitcnt vmcnt(8) lgkmcnt(0)" ::: "memory");
        } else {
            asm volatile("s_waitcnt vmcnt(0) lgkmcnt(0)" ::: "memory");
        }
        __builtin_amdgcn_sched_barrier(0);
        __builtin_amdgcn_s_barrier();
        __builtin_amdgcn_sched_barrier(0);
        __builtin_amdgcn_s_setprio(1);
#pragma unroll
        for (int ks = 0; ks < 2; ks++) {
            int bro = ks ? bro1 : bro0;
            f16x8 bf[4];
#pragma unroll
            for (int n = 0; n < 4; n++)
                bf[n] = *(const f16x8*)(sBc + ((wn * 64 + n * 16 + lr) * 128) + bro);
#pragma unroll
            for (int m = 0; m < 4; m++) {
                f16x8 av = *(const f16x8*)(sAc + ((wm * 64 + m * 16 + lr) * 128) + bro);
#pragma unroll
                for (int n = 0; n < 4; n++)
                    acc[m][n] = __builtin_amdgcn_mfma_f32_16x16x32_f16(av, bf[n], acc[m][n], 0, 0, 0);
            }
        }
        __builtin_amdgcn_s_setprio(0);
    }

    int row0 = mb * 128 + wm * 64;
    int col0 = nb * 128 + wn * 64;
#pragma unroll
    for (int m = 0; m < 4; m++) {
        int rb = row0 + m * 16 + sg * 4;
        int toks[4]; float wts[4];
#pragma unroll
        for (int j = 0; j < 4; j++) {
            int s = base + rb + j;
            toks[j] = slot_tok[s];
            wts[j]  = slot_w[s];
        }
#pragma unroll
        for (int n = 0; n < 4; n++) {
            int col = col0 + n * 16 + lr;
            f32x4 v = acc[m][n];
#pragma unroll
            for (int j = 0; j < 4; j++)
                atomicAdd(&out[(size_t)toks[j] * H_DIM + col], v[j] * wts[j]);
        }
    }
}

// ---------------- launcher ----------------
extern "C" void kernel_launch(void* const* d_in, const int* in_sizes, int n_in,
                              void* d_out, int out_size, void* d_ws, size_t ws_size,
                              hipStream_t stream) {
    const float* x  = (const float*)d_in[0];
    const float* wg = (const float*)d_in[1];
    const float* w1 = (const float*)d_in[2];
    const float* w3 = (const float*)d_in[3];
    const float* w2 = (const float*)d_in[4];
    float* out = (float*)d_out;
    float* logits = out + (size_t)T_TOK * H_DIM;

    char* ws = (char*)d_ws;
    _Float16* hbuf = (_Float16*)ws;                       // 73.4 MB
    _Float16* xb   = hbuf + (size_t)MAX_SLOTS * F_DIM;    // 8.4 MB
    char* p = (char*)(xb + (size_t)T_TOK * H_DIM);
    int*   slot_tok = (int*)p;   p += MAX_SLOTS * 4;
    float* slot_w   = (float*)p; p += MAX_SLOTS * 4;
    int*   tk_e     = (int*)p;   p += T_TOK * 2 * 4;
    float* tk_w     = (float*)p; p += T_TOK * 2 * 4;
    int*   meta     = (int*)p;   // 32 ints

    hipMemsetAsync(d_out, 0, (size_t)out_size * sizeof(float), stream);
    hipMemsetAsync(meta, 0, 32 * sizeof(int), stream);

    cvtx_kernel<<<dim3((size_t)T_TOK * H_DIM / (256 * 8)), 256, 0, stream>>>(x, xb);
    router_kernel<<<dim3(T_TOK / 4), 256, 0, stream>>>(x, wg, logits, tk_e, tk_w, meta);
    scan_kernel<<<dim3(1), 64, 0, stream>>>(meta, slot_tok, slot_w);
    assign_kernel<<<dim3(T_TOK / 256), 256, 0, stream>>>(tk_e, tk_w, meta, slot_tok, slot_w);

    // ffn1: grid.x = F_DIM/64 = 112 (112 % 8 == 0 -> same-B-panel mb-blocks share XCD)
    ffn1_kernel<<<dim3(F_DIM / 64, 16, E_NUM), 256, 0, stream>>>(xb, w1, w3, slot_tok, meta, hbuf);
    // ffn2: grid.x = H_DIM/128 = 16 (16 % 8 == 0)
    ffn2_kernel<<<dim3(H_DIM / 128, 16, E_NUM), 256, 0, stream>>>(hbuf, w2, slot_tok, slot_w, meta, out);
}

// Round 5
// 1203.249 us; speedup vs baseline: 4.0132x; 4.0132x over previous
//
#include <hip/hip_runtime.h>

#define T_TOK 2048
#define H_DIM 2048
#define F_DIM 7168
#define E_NUM 8
#define MAX_SLOTS 5120   // 4096 used slots + per-expert pad to 128
#define N13 (2 * F_DIM)  // 14336 combined w1/w3 columns

typedef __attribute__((ext_vector_type(8))) _Float16 f16x8;
typedef __attribute__((ext_vector_type(4))) float    f32x4;

// async global->LDS, 16B per lane; LDS dest wave-uniform base + lane*16
#define GLL(g, l) __builtin_amdgcn_global_load_lds(                          \
    (const __attribute__((address_space(1))) void*)(g),                      \
    (__attribute__((address_space(3))) void*)(l), 16, 0, 0)

// ---------------- conversion kernels ----------------

// interleaved w13h: combined col c: blk=c>>6, sub=c&63; src=(sub<32?w1:w3),
// f = blk*32 + (sub&31).  One block per (e,c) row, 2048 elems.
__global__ __launch_bounds__(256) void cvt13_kernel(const float* __restrict__ w1,
                                                    const float* __restrict__ w3,
                                                    _Float16* __restrict__ w13h) {
    int b = blockIdx.x;                 // e*N13 + c
    int e = b / N13;
    int c = b - e * N13;
    int blk = c >> 6, sub = c & 63;
    int f = blk * 32 + (sub & 31);
    const float* src = (sub < 32 ? w1 : w3) + ((size_t)e * F_DIM + f) * H_DIM + threadIdx.x * 8;
    _Float16* dst = w13h + (size_t)b * H_DIM + threadIdx.x * 8;
    float4 a = *(const float4*)src;
    float4 bb = *(const float4*)(src + 4);
    f16x8 h;
    h[0]=(_Float16)a.x;  h[1]=(_Float16)a.y;  h[2]=(_Float16)a.z;  h[3]=(_Float16)a.w;
    h[4]=(_Float16)bb.x; h[5]=(_Float16)bb.y; h[6]=(_Float16)bb.z; h[7]=(_Float16)bb.w;
    *(f16x8*)dst = h;
}

__global__ __launch_bounds__(256) void cvtw_kernel(const float* __restrict__ src,
                                                   _Float16* __restrict__ dst) {
    size_t i = ((size_t)blockIdx.x * 256 + threadIdx.x) * 8;
    float4 a = *(const float4*)(src + i);
    float4 b = *(const float4*)(src + i + 4);
    f16x8 h;
    h[0]=(_Float16)a.x; h[1]=(_Float16)a.y; h[2]=(_Float16)a.z; h[3]=(_Float16)a.w;
    h[4]=(_Float16)b.x; h[5]=(_Float16)b.y; h[6]=(_Float16)b.z; h[7]=(_Float16)b.w;
    *(f16x8*)(dst + i) = h;
}

// ---------------- router / bucketing ----------------

__global__ __launch_bounds__(256) void router_kernel(
    const float* __restrict__ x, const float* __restrict__ wg,
    float* __restrict__ logits_out, int* __restrict__ tk_e,
    float* __restrict__ tk_w, int* __restrict__ meta) {
    int wave = threadIdx.x >> 6;
    int lane = threadIdx.x & 63;
    int t = blockIdx.x * 4 + wave;
    const float* xr = x + (size_t)t * H_DIM;

    float xv[32];
#pragma unroll
    for (int i = 0; i < 8; i++) {
        float4 v = *(const float4*)(xr + i * 256 + lane * 4);
        xv[i*4+0] = v.x; xv[i*4+1] = v.y; xv[i*4+2] = v.z; xv[i*4+3] = v.w;
    }
    float lg[E_NUM];
#pragma unroll
    for (int e = 0; e < E_NUM; e++) {
        const float* wr = wg + (size_t)e * H_DIM;
        float acc = 0.f;
#pragma unroll
        for (int i = 0; i < 8; i++) {
            float4 v = *(const float4*)(wr + i * 256 + lane * 4);
            acc += xv[i*4+0]*v.x + xv[i*4+1]*v.y + xv[i*4+2]*v.z + xv[i*4+3]*v.w;
        }
#pragma unroll
        for (int s = 32; s > 0; s >>= 1) acc += __shfl_xor(acc, s, 64);
        lg[e] = acc;
    }
    if (lane == 0) {
        float b0 = -3e38f, b1 = -3e38f; int i0 = 0, i1 = 0;
#pragma unroll
        for (int e = 0; e < E_NUM; e++) {
            float le = lg[e];
            if (le > b0)      { b1 = b0; i1 = i0; b0 = le; i0 = e; }
            else if (le > b1) { b1 = le; i1 = e; }
        }
        float w0 = 1.f / (1.f + __expf(b1 - b0));
        float w1v = 1.f - w0;
#pragma unroll
        for (int e = 0; e < E_NUM; e++) logits_out[(size_t)t * E_NUM + e] = lg[e];
        tk_e[t*2+0] = i0; tk_w[t*2+0] = w0;
        tk_e[t*2+1] = i1; tk_w[t*2+1] = w1v;
        atomicAdd(&meta[i0], 1);
        atomicAdd(&meta[i1], 1);
    }
}

// meta layout: [0..7]=cnt, [8..15]=cnt_pad128, [16..23]=base, [24..31]=fill
__global__ void scan_kernel(int* __restrict__ meta, int* __restrict__ slot_tok,
                            float* __restrict__ slot_w) {
    int lane = threadIdx.x;  // 64 threads
    int cnts[E_NUM], pads[E_NUM], bases[E_NUM];
    int run = 0;
#pragma unroll
    for (int e = 0; e < E_NUM; e++) {
        cnts[e] = meta[e];
        pads[e] = (cnts[e] + 127) & ~127;
        bases[e] = run;
        run += pads[e];
    }
    if (lane < E_NUM) { meta[8 + lane] = pads[lane]; meta[16 + lane] = bases[lane]; }
    for (int e = 0; e < E_NUM; e++)
        for (int i = cnts[e] + lane; i < pads[e]; i += 64) {
            slot_tok[bases[e] + i] = 0;
            slot_w[bases[e] + i] = 0.f;
        }
}

__global__ __launch_bounds__(256) void assign_kernel(
    const int* __restrict__ tk_e, const float* __restrict__ tk_w,
    int* __restrict__ meta, int* __restrict__ slot_tok, float* __restrict__ slot_w) {
    int t = blockIdx.x * 256 + threadIdx.x;
    if (t >= T_TOK) return;
#pragma unroll
    for (int k = 0; k < 2; k++) {
        int e = tk_e[t*2+k];
        int pos = atomicAdd(&meta[24 + e], 1);
        int s = meta[16 + e] + pos;
        slot_tok[s] = t;
        slot_w[s] = tk_w[t*2+k];
    }
}

// ---------------- ffn1: 128(M) x 256(N of w13) x K64, ring-3, counted vmcnt ----------------
// 8 waves 2(M)x4(N); per-wave 64x64 out = acc[4][4]; per K-tile 2 phases x 16 MFMA.
__global__ __launch_bounds__(512, 2) void ffn1_kernel(
    const _Float16* __restrict__ xb, const _Float16* __restrict__ w13h,
    const int* __restrict__ slot_tok, const int* __restrict__ meta,
    _Float16* __restrict__ hbuf) {
    int e = blockIdx.z;
    int cntpad = meta[8 + e];
    int mb = blockIdx.y;
    if (mb * 128 >= cntpad) return;
    int base = meta[16 + e];
    int nb = blockIdx.x;

    __shared__ _Float16 sA[3][128][64];   // 48 KB
    __shared__ _Float16 sB[3][256][64];   // 96 KB

    int tid  = threadIdx.x;
    int lane = tid & 63;
    int wave = tid >> 6;                  // 0..7
    int wm = wave >> 2, wn = wave & 3;    // 2(M) x 4(N)
    int w8 = wave * 8;
    int lr = lane & 15;
    int sg = lane >> 4;                   // 0..3
    int sw7 = lane & 7;
    int so0 = ((sg    ) ^ sw7) * 8;       // swizzled 16B-slot (halves), k-half 0
    int so1 = ((sg + 4) ^ sw7) * 8;       // k-half 1
    int rb  = lr * 64;

    // staging source addresses (pre-swizzled col slot; LDS dest stays linear)
    int rsub = lane >> 3;
    int sl   = sw7 ^ rsub;
    const _Float16* aG[2];
#pragma unroll
    for (int q = 0; q < 2; q++) {
        int row = q * 64 + w8 + rsub;     // 0..127
        int tok = slot_tok[base + mb * 128 + row];
        aG[q] = xb + (size_t)tok * H_DIM + sl * 8;
    }
    const _Float16* bG[4];
#pragma unroll
    for (int q = 0; q < 4; q++)
        bG[q] = w13h + ((size_t)e * N13 + (size_t)nb * 256 + q * 64 + w8 + rsub) * H_DIM + sl * 8;

    f32x4 zero = {0.f, 0.f, 0.f, 0.f};
    f32x4 acc[4][4];
#pragma unroll
    for (int m = 0; m < 4; m++)
#pragma unroll
        for (int n = 0; n < 4; n++) acc[m][n] = zero;

    const int NT = H_DIM / 64;  // 32

    // prologue: stage tiles 0 (buf0) and 1 (buf1); 6 GLL each
#pragma unroll
    for (int t0 = 0; t0 < 2; t0++) {
        int k = t0 * 64;
        GLL(aG[0] + k, &sA[t0][w8][0]);
        GLL(aG[1] + k, &sA[t0][64 + w8][0]);
#pragma unroll
        for (int q = 0; q < 4; q++) GLL(bG[q] + k, &sB[t0][q * 64 + w8][0]);
    }
    asm volatile("s_waitcnt vmcnt(6)" ::: "memory");   // tile0 complete, tile1 in flight
    __builtin_amdgcn_sched_barrier(0);
    __builtin_amdgcn_s_barrier();
    __builtin_amdgcn_sched_barrier(0);

    for (int t = 0; t < NT; ++t) {
        int r  = t % 3;
        int r2 = (t + 2) % 3;
        int k2 = (t + 2) * 64;
        const _Float16* Ab = &sA[r][wm * 64][0];
        const _Float16* Bb = &sB[r][wn * 64][0];

        // ---- phase 0 (k-half 0) ----
        f16x8 a0[4], b0[4];
#pragma unroll
        for (int n = 0; n < 4; n++) b0[n] = *(const f16x8*)(const void*)(Bb + n * 1024 + rb + so0);
#pragma unroll
        for (int m = 0; m < 4; m++) a0[m] = *(const f16x8*)(const void*)(Ab + m * 1024 + rb + so0);
        if (t + 2 < NT) {
            GLL(aG[0] + k2, &sA[r2][w8][0]);
            GLL(aG[1] + k2, &sA[r2][64 + w8][0]);
            GLL(bG[0] + k2, &sB[r2][w8][0]);
        }
        __builtin_amdgcn_sched_barrier(0);
        __builtin_amdgcn_s_barrier();
        __builtin_amdgcn_sched_barrier(0);
        __builtin_amdgcn_s_setprio(1);
#pragma unroll
        for (int m = 0; m < 4; m++)
#pragma unroll
            for (int n = 0; n < 4; n++)
                acc[m][n] = __builtin_amdgcn_mfma_f32_16x16x32_f16(a0[m], b0[n], acc[m][n], 0, 0, 0);
        __builtin_amdgcn_s_setprio(0);
        __builtin_amdgcn_sched_barrier(0);
        __builtin_amdgcn_s_barrier();
        __builtin_amdgcn_sched_barrier(0);

        // ---- phase 1 (k-half 1) ----
        f16x8 a1[4], b1[4];
#pragma unroll
        for (int n = 0; n < 4; n++) b1[n] = *(const f16x8*)(const void*)(Bb + n * 1024 + rb + so1);
#pragma unroll
        for (int m = 0; m < 4; m++) a1[m] = *(const f16x8*)(const void*)(Ab + m * 1024 + rb + so1);
        if (t + 2 < NT) {
            GLL(bG[1] + k2, &sB[r2][64 + w8][0]);
            GLL(bG[2] + k2, &sB[r2][128 + w8][0]);
            GLL(bG[3] + k2, &sB[r2][192 + w8][0]);
        }
        // cross-tile gate: complete tile t+1's 6 loads, keep tile t+2's 6 in flight
        if (t < NT - 2) asm volatile("s_waitcnt vmcnt(6)" ::: "memory");
        else            asm volatile("s_waitcnt vmcnt(0)" ::: "memory");
        __builtin_amdgcn_sched_barrier(0);
        __builtin_amdgcn_s_barrier();
        __builtin_amdgcn_sched_barrier(0);
        __builtin_amdgcn_s_setprio(1);
#pragma unroll
        for (int m = 0; m < 4; m++)
#pragma unroll
            for (int n = 0; n < 4; n++)
                acc[m][n] = __builtin_amdgcn_mfma_f32_16x16x32_f16(a1[m], b1[n], acc[m][n], 0, 0, 0);
        __builtin_amdgcn_s_setprio(0);
        __builtin_amdgcn_sched_barrier(0);
        __builtin_amdgcn_s_barrier();
        __builtin_amdgcn_sched_barrier(0);
    }

    // epilogue: n∈{0,1}=w1, n+2=w3 (same f); hv = silu(a1)*a3 -> hbuf fp16
    int fb = (nb * 4 + wn) * 32;
#pragma unroll
    for (int m = 0; m < 4; m++) {
#pragma unroll
        for (int j = 0; j < 4; j++) {
            int re = mb * 128 + wm * 64 + m * 16 + sg * 4 + j;
            size_t srow = (size_t)(base + re) * F_DIM;
#pragma unroll
            for (int n = 0; n < 2; n++) {
                float a1v = acc[m][n][j], a3v = acc[m][n + 2][j];
                float hv = a1v * a3v / (1.f + __expf(-a1v));
                hbuf[srow + fb + n * 16 + lr] = (_Float16)hv;
            }
        }
    }
}

// ---------------- ffn2: 128(M) x 256(N of H) x K64, same template ----------------
__global__ __launch_bounds__(512, 2) void ffn2_kernel(
    const _Float16* __restrict__ hbuf, const _Float16* __restrict__ w2h,
    const int* __restrict__ slot_tok, const float* __restrict__ slot_w,
    const int* __restrict__ meta, float* __restrict__ out) {
    int e = blockIdx.z;
    int cntpad = meta[8 + e];
    int mb = blockIdx.y;
    if (mb * 128 >= cntpad) return;
    int base = meta[16 + e];
    int nb = blockIdx.x;

    __shared__ _Float16 sA[3][128][64];
    __shared__ _Float16 sB[3][256][64];

    int tid  = threadIdx.x;
    int lane = tid & 63;
    int wave = tid >> 6;
    int wm = wave >> 2, wn = wave & 3;
    int w8 = wave * 8;
    int lr = lane & 15;
    int sg = lane >> 4;
    int sw7 = lane & 7;
    int so0 = ((sg    ) ^ sw7) * 8;
    int so1 = ((sg + 4) ^ sw7) * 8;
    int rb  = lr * 64;

    int rsub = lane >> 3;
    int sl   = sw7 ^ rsub;
    const _Float16* aG[2];
#pragma unroll
    for (int q = 0; q < 2; q++)
        aG[q] = hbuf + (size_t)(base + mb * 128 + q * 64 + w8 + rsub) * F_DIM + sl * 8;
    const _Float16* bG[4];
#pragma unroll
    for (int q = 0; q < 4; q++)
        bG[q] = w2h + ((size_t)e * H_DIM + (size_t)nb * 256 + q * 64 + w8 + rsub) * F_DIM + sl * 8;

    f32x4 zero = {0.f, 0.f, 0.f, 0.f};
    f32x4 acc[4][4];
#pragma unroll
    for (int m = 0; m < 4; m++)
#pragma unroll
        for (int n = 0; n < 4; n++) acc[m][n] = zero;

    const int NT = F_DIM / 64;  // 112

#pragma unroll
    for (int t0 = 0; t0 < 2; t0++) {
        int k = t0 * 64;
        GLL(aG[0] + k, &sA[t0][w8][0]);
        GLL(aG[1] + k, &sA[t0][64 + w8][0]);
#pragma unroll
        for (int q = 0; q < 4; q++) GLL(bG[q] + k, &sB[t0][q * 64 + w8][0]);
    }
    asm volatile("s_waitcnt vmcnt(6)" ::: "memory");
    __builtin_amdgcn_sched_barrier(0);
    __builtin_amdgcn_s_barrier();
    __builtin_amdgcn_sched_barrier(0);

    for (int t = 0; t < NT; ++t) {
        int r  = t % 3;
        int r2 = (t + 2) % 3;
        int k2 = (t + 2) * 64;
        const _Float16* Ab = &sA[r][wm * 64][0];
        const _Float16* Bb = &sB[r][wn * 64][0];

        f16x8 a0[4], b0[4];
#pragma unroll
        for (int n = 0; n < 4; n++) b0[n] = *(const f16x8*)(const void*)(Bb + n * 1024 + rb + so0);
#pragma unroll
        for (int m = 0; m < 4; m++) a0[m] = *(const f16x8*)(const void*)(Ab + m * 1024 + rb + so0);
        if (t + 2 < NT) {
            GLL(aG[0] + k2, &sA[r2][w8][0]);
            GLL(aG[1] + k2, &sA[r2][64 + w8][0]);
            GLL(bG[0] + k2, &sB[r2][w8][0]);
        }
        __builtin_amdgcn_sched_barrier(0);
        __builtin_amdgcn_s_barrier();
        __builtin_amdgcn_sched_barrier(0);
        __builtin_amdgcn_s_setprio(1);
#pragma unroll
        for (int m = 0; m < 4; m++)
#pragma unroll
            for (int n = 0; n < 4; n++)
                acc[m][n] = __builtin_amdgcn_mfma_f32_16x16x32_f16(a0[m], b0[n], acc[m][n], 0, 0, 0);
        __builtin_amdgcn_s_setprio(0);
        __builtin_amdgcn_sched_barrier(0);
        __builtin_amdgcn_s_barrier();
        __builtin_amdgcn_sched_barrier(0);

        f16x8 a1[4], b1[4];
#pragma unroll
        for (int n = 0; n < 4; n++) b1[n] = *(const f16x8*)(const void*)(Bb + n * 1024 + rb + so1);
#pragma unroll
        for (int m = 0; m < 4; m++) a1[m] = *(const f16x8*)(const void*)(Ab + m * 1024 + rb + so1);
        if (t + 2 < NT) {
            GLL(bG[1] + k2, &sB[r2][64 + w8][0]);
            GLL(bG[2] + k2, &sB[r2][128 + w8][0]);
            GLL(bG[3] + k2, &sB[r2][192 + w8][0]);
        }
        if (t < NT - 2) asm volatile("s_waitcnt vmcnt(6)" ::: "memory");
        else            asm volatile("s_waitcnt vmcnt(0)" ::: "memory");
        __builtin_amdgcn_sched_barrier(0);
        __builtin_amdgcn_s_barrier();
        __builtin_amdgcn_sched_barrier(0);
        __builtin_amdgcn_s_setprio(1);
#pragma unroll
        for (int m = 0; m < 4; m++)
#pragma unroll
            for (int n = 0; n < 4; n++)
                acc[m][n] = __builtin_amdgcn_mfma_f32_16x16x32_f16(a1[m], b1[n], acc[m][n], 0, 0, 0);
        __builtin_amdgcn_s_setprio(0);
        __builtin_amdgcn_sched_barrier(0);
        __builtin_amdgcn_s_barrier();
        __builtin_amdgcn_sched_barrier(0);
    }

    int row0 = mb * 128 + wm * 64;
    int col0 = nb * 256 + wn * 64;
#pragma unroll
    for (int m = 0; m < 4; m++) {
        int rbw = row0 + m * 16 + sg * 4;
        int toks[4]; float wts[4];
#pragma unroll
        for (int j = 0; j < 4; j++) {
            int s = base + rbw + j;
            toks[j] = slot_tok[s];
            wts[j]  = slot_w[s];
        }
#pragma unroll
        for (int n = 0; n < 4; n++) {
            int col = col0 + n * 16 + lr;
            f32x4 v = acc[m][n];
#pragma unroll
            for (int j = 0; j < 4; j++)
                atomicAdd(&out[(size_t)toks[j] * H_DIM + col], v[j] * wts[j]);
        }
    }
}

// ---------------- launcher ----------------
extern "C" void kernel_launch(void* const* d_in, const int* in_sizes, int n_in,
                              void* d_out, int out_size, void* d_ws, size_t ws_size,
                              hipStream_t stream) {
    const float* x  = (const float*)d_in[0];
    const float* wg = (const float*)d_in[1];
    const float* w1 = (const float*)d_in[2];
    const float* w3 = (const float*)d_in[3];
    const float* w2 = (const float*)d_in[4];
    float* out = (float*)d_out;
    float* logits = out + (size_t)T_TOK * H_DIM;

    const size_t WELEM = (size_t)E_NUM * F_DIM * H_DIM;   // 117,440,512

    char* ws = (char*)d_ws;
    _Float16* w13h = (_Float16*)ws;                       // 448 MiB
    _Float16* w2h  = w13h + 2 * WELEM;                    // 224 MiB
    _Float16* hbuf = w2h + WELEM;                         // 70 MiB
    _Float16* xb   = hbuf + (size_t)MAX_SLOTS * F_DIM;    // 8 MiB
    char* p = (char*)(xb + (size_t)T_TOK * H_DIM);
    int*   slot_tok = (int*)p;   p += MAX_SLOTS * 4;
    float* slot_w   = (float*)p; p += MAX_SLOTS * 4;
    int*   tk_e     = (int*)p;   p += T_TOK * 2 * 4;
    float* tk_w     = (float*)p; p += T_TOK * 2 * 4;
    int*   meta     = (int*)p;   // 32 ints

    hipMemsetAsync(d_out, 0, (size_t)out_size * sizeof(float), stream);
    hipMemsetAsync(meta, 0, 32 * sizeof(int), stream);

    cvt13_kernel<<<dim3(E_NUM * N13), 256, 0, stream>>>(w1, w3, w13h);
    cvtw_kernel<<<dim3(WELEM / (256 * 8)), 256, 0, stream>>>(w2, w2h);
    cvtw_kernel<<<dim3((size_t)T_TOK * H_DIM / (256 * 8)), 256, 0, stream>>>(x, xb);

    router_kernel<<<dim3(T_TOK / 4), 256, 0, stream>>>(x, wg, logits, tk_e, tk_w, meta);
    scan_kernel<<<dim3(1), 64, 0, stream>>>(meta, slot_tok, slot_w);
    assign_kernel<<<dim3(T_TOK / 256), 256, 0, stream>>>(tk_e, tk_w, meta, slot_tok, slot_w);

    ffn1_kernel<<<dim3(N13 / 256, 16, E_NUM), 512, 0, stream>>>(xb, w13h, slot_tok, meta, hbuf);
    ffn2_kernel<<<dim3(H_DIM / 256, 16, E_NUM), 512, 0, stream>>>(hbuf, w2h, slot_tok, slot_w, meta, out);
}